// Round 25
// baseline (125.579 us; speedup 1.0000x reference)
//
#include <hip/hip_runtime.h>
#include <hip/hip_bf16.h>
#include <math.h>

typedef unsigned short u16;
typedef unsigned int u32;
typedef __attribute__((ext_vector_type(8))) short bf8;   // 8 bf16 = 4 VGPR
typedef __attribute__((ext_vector_type(4))) float f4;    // 4 f32 acc

__device__ __forceinline__ u16 bfhi(float x) {
    u32 u = __float_as_uint(x);
    u32 r = u + 0x7FFFu + ((u >> 16) & 1u);   // RNE
    return (u16)(r >> 16);
}
__device__ __forceinline__ float bf2f(u16 h) { return __uint_as_float(((u32)h) << 16); }
// packed RNE f32x2 -> bf16x2 (compiler emits v_cvt_pk_bf16_f32)
__device__ __forceinline__ u32 cvtpk(float a, float b) {
    __hip_bfloat162 h = __float22bfloat162_rn(make_float2(a, b));
    u32 r;
    __builtin_memcpy(&r, &h, 4);
    return r;
}

// ================= graph build: zero-global-atomic bucketed CSR =================
// bucket = col >> 6. CH = 2048 edges per workgroup -> nwg = 391 blocks (full CU use).

#define CHUNK 2048

__global__ __launch_bounds__(256) void bucket_hist(const int* __restrict__ col,
                                                   int* __restrict__ M, int E, int nbuk, int nwg) {
    __shared__ int h[1024];
    const int tid = threadIdx.x;
    for (int i = tid; i < 1024; i += 256) h[i] = 0;
    __syncthreads();
    int base = blockIdx.x * CHUNK;
    for (int i = tid; i < CHUNK; i += 256) {
        int e = base + i;
        if (e < E) atomicAdd(&h[col[e] >> 6], 1);   // LDS atomic
    }
    __syncthreads();
    for (int b = tid; b < nbuk; b += 256) M[b * nwg + blockIdx.x] = h[b];
}

// one 64-lane wave per bucket: shfl inclusive scan over nwg chunk-counts (carry-chained)
__global__ __launch_bounds__(256) void col_scan_wave(int* __restrict__ M, int* __restrict__ bsum,
                                                     int nbuk, int nwg) {
    int wave = (blockIdx.x * blockDim.x + threadIdx.x) >> 6;
    int lane = threadIdx.x & 63;
    if (wave >= nbuk) return;
    int* Mb = M + (size_t)wave * nwg;
    int carry = 0;
    for (int base = 0; base < nwg; base += 64) {
        int w = base + lane;
        int v = (w < nwg) ? Mb[w] : 0;
        int x = v;
        for (int off = 1; off < 64; off <<= 1) {
            int y = __shfl_up(x, off);
            if (lane >= off) x += y;
        }
        if (w < nwg) Mb[w] = carry + x - v;   // exclusive
        carry += __shfl(x, 63);
    }
    if (lane == 0) bsum[wave] = carry;
}

__global__ void bucket_scan(const int* __restrict__ bsum, int* __restrict__ boff,
                            int* __restrict__ rowptr, int nbuk, int n, int E) {
    __shared__ int sh[1024];
    const int tid = threadIdx.x;
    int v = (tid < nbuk) ? bsum[tid] : 0;
    sh[tid] = v; __syncthreads();
    for (int off = 1; off < 1024; off <<= 1) {
        int x = sh[tid];
        int w = (tid >= off) ? sh[tid - off] : 0;
        __syncthreads();
        sh[tid] = x + w;
        __syncthreads();
    }
    if (tid < nbuk) boff[tid] = sh[tid] - v;
    if (tid == 0) { boff[nbuk] = E; rowptr[n] = E; }
}

__global__ __launch_bounds__(256) void bucket_scatter(const int* __restrict__ row,
                                                      const int* __restrict__ col,
                                                      const int* __restrict__ M,
                                                      const int* __restrict__ boff,
                                                      int2* __restrict__ ebuf, int E, int nwg) {
    __shared__ int h[1024];
    const int tid = threadIdx.x;
    for (int i = tid; i < 1024; i += 256) h[i] = 0;
    __syncthreads();
    int base = blockIdx.x * CHUNK;
    for (int i = tid; i < CHUNK; i += 256) {
        int e = base + i;
        if (e < E) {
            int c = col[e], b = c >> 6;
            int rank = atomicAdd(&h[b], 1);  // LDS
            int slot = boff[b] + M[b * nwg + blockIdx.x] + rank;
            ebuf[slot] = make_int2(c, row[e]);
        }
    }
}

__global__ __launch_bounds__(256) void bucket_finalize(const int2* __restrict__ ebuf,
                                                       const int* __restrict__ boff,
                                                       int* __restrict__ rowptr,
                                                       int* __restrict__ csrc,
                                                       float* __restrict__ dinv, int n) {
    __shared__ int h[64];
    __shared__ int curs[64];
    const int b = blockIdx.x, tid = threadIdx.x;
    const int n0 = b << 6;
    const int beg = boff[b], end = boff[b + 1];
    if (tid < 64) h[tid] = 0;
    __syncthreads();
    for (int i = beg + tid; i < end; i += 256) atomicAdd(&h[ebuf[i].x & 63], 1);
    __syncthreads();
    if (tid < 64) {                    // first wave: 64-lane shfl scan
        int cnt = h[tid];
        int v = cnt;
        for (int off = 1; off < 64; off <<= 1) {
            int w = __shfl_up(v, off);
            if (tid >= off) v += w;
        }
        int cursor = beg + v - cnt;    // exclusive
        curs[tid] = cursor;
        int node = n0 + tid;
        if (node < n) {
            rowptr[node] = cursor;
            dinv[node] = rsqrtf((float)(cnt + 1));   // +1 self loop
        }
    }
    __syncthreads();
    for (int i = beg + tid; i < end; i += 256) {
        int2 e = ebuf[i];
        int slot = atomicAdd(&curs[e.x & 63], 1);    // LDS
        csrc[slot] = e.y;
    }
}

// ------- fused agg1 + layer-2 GEMM -------
__global__ __launch_bounds__(256) void agg1_gemm2(
    const int* __restrict__ rowptr, const int* __restrict__ csrc,
    const u16* __restrict__ hs, const float* __restrict__ dinv,
    const float* __restrict__ b1, const float* __restrict__ W2,
    u16* __restrict__ hs2, int n) {
    __shared__ float w2s[64][33];   // pad 33
    const int tid = threadIdx.x;
    for (int i = tid; i < 64 * 32; i += 256) w2s[i >> 5][i & 31] = W2[i];
    __syncthreads();

    int gid = blockIdx.x * blockDim.x + tid;
    int node = gid >> 3, lane = gid & 7;
    if (node >= n) return;
    int f0 = lane * 8;
    int beg = rowptr[node], end = rowptr[node + 1];
    float s[8] = {0.f, 0.f, 0.f, 0.f, 0.f, 0.f, 0.f, 0.f};
    auto acc8 = [&](uint4 v) {
        u32 a0 = v.x, a1 = v.y, a2 = v.z, a3 = v.w;
        s[0] += bf2f((u16)a0); s[1] += bf2f((u16)(a0 >> 16));
        s[2] += bf2f((u16)a1); s[3] += bf2f((u16)(a1 >> 16));
        s[4] += bf2f((u16)a2); s[5] += bf2f((u16)(a2 >> 16));
        s[6] += bf2f((u16)a3); s[7] += bf2f((u16)(a3 >> 16));
    };
    int j = beg;
    for (; j + 3 < end; j += 4) {
        int s0 = csrc[j], s1 = csrc[j + 1], s2 = csrc[j + 2], s3 = csrc[j + 3];
        uint4 v0 = *(const uint4*)&hs[(size_t)s0 * 64 + f0];
        uint4 v1 = *(const uint4*)&hs[(size_t)s1 * 64 + f0];
        uint4 v2 = *(const uint4*)&hs[(size_t)s2 * 64 + f0];
        uint4 v3 = *(const uint4*)&hs[(size_t)s3 * 64 + f0];
        acc8(v0); acc8(v1); acc8(v2); acc8(v3);
    }
    for (; j < end; ++j) acc8(*(const uint4*)&hs[(size_t)csrc[j] * 64 + f0]);
    acc8(*(const uint4*)&hs[(size_t)node * 64 + f0]);   // self loop

    float di = dinv[node];
    float r[8];
#pragma unroll
    for (int c = 0; c < 8; ++c) r[c] = fmaxf(di * s[c] + b1[f0 + c], 0.f);

    float part[32];
#pragma unroll
    for (int c = 0; c < 32; ++c) part[c] = 0.f;
#pragma unroll
    for (int jj = 0; jj < 8; ++jj) {
        float rv = r[jj];
#pragma unroll
        for (int c = 0; c < 32; ++c) part[c] = fmaf(rv, w2s[f0 + jj][c], part[c]);
    }
#pragma unroll
    for (int m = 1; m < 8; m <<= 1) {
#pragma unroll
        for (int c = 0; c < 32; ++c) part[c] += __shfl_xor(part[c], m);
    }
    int c0 = lane * 4;
    u32 p0 = cvtpk(part[c0] * di, part[c0 + 1] * di);
    u32 p1 = cvtpk(part[c0 + 2] * di, part[c0 + 3] * di);
    *(uint2*)&hs2[(size_t)node * 32 + c0] = make_uint2(p0, p1);
}

// ------- CSR gather aggregation from bf16 rows (layer-2 agg -> emb) -------
template<int F, bool OV>
__global__ void agg_finalize_bf16(const int* __restrict__ rowptr, const int* __restrict__ csrc,
                                  const u16* __restrict__ hs, const float* __restrict__ dinv,
                                  const float* __restrict__ b, float* __restrict__ out,
                                  int n, int ostride, int col0) {
    constexpr int L = F / 8;                 // lanes per node
    int tid = blockIdx.x * blockDim.x + threadIdx.x;
    int node = tid / L, lane = tid % L;
    if (node >= n) return;
    int f0 = lane * 8;                       // u16 index
    int beg = rowptr[node], end = rowptr[node + 1];
    float s[8] = {0.f, 0.f, 0.f, 0.f, 0.f, 0.f, 0.f, 0.f};
    auto acc8 = [&](uint4 v) {
        u32 a0 = v.x, a1 = v.y, a2 = v.z, a3 = v.w;
        s[0] += bf2f((u16)a0); s[1] += bf2f((u16)(a0 >> 16));
        s[2] += bf2f((u16)a1); s[3] += bf2f((u16)(a1 >> 16));
        s[4] += bf2f((u16)a2); s[5] += bf2f((u16)(a2 >> 16));
        s[6] += bf2f((u16)a3); s[7] += bf2f((u16)(a3 >> 16));
    };
    int j = beg;
    for (; j + 3 < end; j += 4) {
        int s0 = csrc[j], s1 = csrc[j + 1], s2 = csrc[j + 2], s3 = csrc[j + 3];
        uint4 v0 = *(const uint4*)&hs[(size_t)s0 * F + f0];
        uint4 v1 = *(const uint4*)&hs[(size_t)s1 * F + f0];
        uint4 v2 = *(const uint4*)&hs[(size_t)s2 * F + f0];
        uint4 v3 = *(const uint4*)&hs[(size_t)s3 * F + f0];
        acc8(v0); acc8(v1); acc8(v2); acc8(v3);
    }
    for (; j < end; ++j) acc8(*(const uint4*)&hs[(size_t)csrc[j] * F + f0]);
    acc8(*(const uint4*)&hs[(size_t)node * F + f0]);   // self loop
    float di = dinv[node];
    float r[8];
#pragma unroll
    for (int c = 0; c < 8; ++c) r[c] = fmaxf(di * s[c] + b[f0 + c], 0.f);
    float* op = &out[(size_t)node * ostride + col0 + f0];
    if (OV) {
        *(float4*)op = make_float4(r[0], r[1], r[2], r[3]);
        *(float4*)(op + 4) = make_float4(r[4], r[5], r[6], r[7]);
    } else {
#pragma unroll
        for (int c = 0; c < 8; ++c) op[c] = r[c];
    }
}

// ---------------- weight pre-swizzle into MFMA B-fragment order ----------------
// tiles: 0..7 Wd1(32x128), 8..39 Wd2(128x128), 40..71 Wd3(128x128), 72 Wp(32x10 pad16),
//        73..88 W1(128x64)
__global__ void wswz_kernel(const float* __restrict__ Wd1, const float* __restrict__ Wd2,
                            const float* __restrict__ Wd3, const float* __restrict__ Wp,
                            const float* __restrict__ W1,
                            u16* __restrict__ whi, u16* __restrict__ wlo) {
    int t = blockIdx.x, l = threadIdx.x;   // 89 blocks x 64 threads
    const float* W; int C, kt, ct;
    if (t < 8)       { W = Wd1; C = 128; kt = 0;            ct = t; }
    else if (t < 40) { W = Wd2; C = 128; kt = (t - 8) >> 3;  ct = (t - 8) & 7; }
    else if (t < 72) { W = Wd3; C = 128; kt = (t - 40) >> 3; ct = (t - 40) & 7; }
    else if (t < 73) { W = Wp;  C = 10;  kt = 0;            ct = 0; }
    else             { W = W1;  C = 64;  kt = (t - 73) >> 2; ct = (t - 73) & 3; }
    int kbase = kt * 32 + (l >> 4) * 8;
    int c = ct * 16 + (l & 15);
    size_t base = (size_t)t * 512 + (size_t)l * 8;
#pragma unroll
    for (int j = 0; j < 8; ++j) {
        float v = (c < C) ? W[(size_t)(kbase + j) * C + c] : 0.f;
        u16 h = bfhi(v);
        whi[base + j] = (u16)h;
        wlo[base + j] = bfhi(v - bf2f(h));
    }
}

// ---------------- GCN layer-1 GEMM via split-bf16 MFMA, bf16 output ----------------
__global__ __launch_bounds__(512) void gemm1_mfma(
    const float* __restrict__ x, const u16* __restrict__ whi, const u16* __restrict__ wlo,
    const float* __restrict__ dinv, u16* __restrict__ outp, int n, int ntiles) {
    __shared__ __align__(16) u16 wH[16][512], wL[16][512];   // 32 KB

    const int tid = threadIdx.x;
    const int l = tid & 63, wv = tid >> 6;
    const int lr = l & 15, lg = l >> 4;
    const int wrow = wv * 16;

    for (int i = tid; i < 16 * 64; i += 512) {
        ((int4*)wH)[i] = ((const int4*)(whi + 73 * 512))[i];
        ((int4*)wL)[i] = ((const int4*)(wlo + 73 * 512))[i];
    }
    __syncthreads();

    for (int t = blockIdx.x; t < ntiles; t += gridDim.x) {
        const int row0 = t * 128;
        int arow = row0 + wrow + lr; if (arow >= n) arow = n - 1;
        const float* src = &x[(size_t)arow * 128];

        f4 acc[4];
#pragma unroll
        for (int ct = 0; ct < 4; ++ct) acc[ct] = (f4){0.f, 0.f, 0.f, 0.f};
#pragma unroll
        for (int kt = 0; kt < 4; ++kt) {
            const float* s = src + kt * 32 + lg * 8;
            float4 v0 = *(const float4*)s, v1 = *(const float4*)(s + 4);
            float xs[8] = {v0.x, v0.y, v0.z, v0.w, v1.x, v1.y, v1.z, v1.w};
            bf8 aH, aL;
#pragma unroll
            for (int j = 0; j < 8; j += 2) {
                u32 hp = cvtpk(xs[j], xs[j + 1]);
                ((u32*)&aH)[j >> 1] = hp;
                float l0 = xs[j] - bf2f((u16)hp);
                float l1 = xs[j + 1] - bf2f((u16)(hp >> 16));
                ((u32*)&aL)[j >> 1] = cvtpk(l0, l1);
            }
            __builtin_amdgcn_s_setprio(1);
#pragma unroll
            for (int ct = 0; ct < 4; ++ct) {
                bf8 bH = *(const bf8*)&wH[kt * 4 + ct][l * 8];
                bf8 bL = *(const bf8*)&wL[kt * 4 + ct][l * 8];
                acc[ct] = __builtin_amdgcn_mfma_f32_16x16x32_bf16(aH, bH, acc[ct], 0, 0, 0);
                acc[ct] = __builtin_amdgcn_mfma_f32_16x16x32_bf16(aL, bH, acc[ct], 0, 0, 0);
                acc[ct] = __builtin_amdgcn_mfma_f32_16x16x32_bf16(aH, bL, acc[ct], 0, 0, 0);
            }
            __builtin_amdgcn_s_setprio(0);
        }
#pragma unroll
        for (int rg = 0; rg < 4; ++rg) {
            int g = row0 + wrow + lg * 4 + rg;
            if (g < n) {
                float di = dinv[g];
                u16* op = &outp[(size_t)g * 64 + lr];
#pragma unroll
                for (int ct = 0; ct < 4; ++ct) op[ct * 16] = bfhi(acc[ct][rg] * di);
            }
        }
    }
}

// ---------------- fully-fused MFMA decoder: 8 waves, 128-row tiles, setprio on MFMA ----------------
__global__ __launch_bounds__(512, 1) void dec_fused(
    const float* __restrict__ obuf,
    const u16* __restrict__ whi, const u16* __restrict__ wlo,
    const float* __restrict__ bp, const float* __restrict__ bd1,
    const float* __restrict__ bd2, const float* __restrict__ bd3,
    float* __restrict__ out, int n, int ntiles) {
    __shared__ __align__(16) u16 wbH[73][512];   // 74752 B
    __shared__ __align__(16) u16 wbL[73][512];   // 74752 B
    __shared__ __align__(16) u32 scr[128][20];   // 10240 B

    const int tid = threadIdx.x;
    const int l = tid & 63, wv = tid >> 6;       // 8 waves
    const int lr = l & 15, lg = l >> 4;
    const int wrow = wv * 16;

    for (int i = tid; i < 73 * 64; i += 512) {
        ((int4*)wbH)[i] = ((const int4*)whi)[i];
        ((int4*)wbL)[i] = ((const int4*)wlo)[i];
    }
    __syncthreads();

    for (int t = blockIdx.x; t < ntiles; t += gridDim.x) {
        const int row0 = t * 128;
        int arow = row0 + wrow + lr; if (arow >= n) arow = n - 1;

        const float* src = &obuf[(size_t)arow * 170 + lg * 8];
        bf8 aH, aL;
#pragma unroll
        for (int i = 0; i < 8; i += 2) {
            float2 v = *(const float2*)(src + i);
            u32 hp = cvtpk(v.x, v.y);
            ((u32*)&aH)[i >> 1] = hp;
            float l0 = v.x - bf2f((u16)hp);
            float l1 = v.y - bf2f((u16)(hp >> 16));
            ((u32*)&aL)[i >> 1] = cvtpk(l0, l1);
        }

        // ---- stage 1 (MFMA cluster at prio 1) ----
        f4 acc1[8];
        __builtin_amdgcn_s_setprio(1);
#pragma unroll
        for (int ct = 0; ct < 8; ++ct) {
            bf8 bH = *(const bf8*)&wbH[ct][l * 8];
            bf8 bL = *(const bf8*)&wbL[ct][l * 8];
            f4 a = (f4){0.f, 0.f, 0.f, 0.f};
            a = __builtin_amdgcn_mfma_f32_16x16x32_bf16(aH, bH, a, 0, 0, 0);
            a = __builtin_amdgcn_mfma_f32_16x16x32_bf16(aL, bH, a, 0, 0, 0);
            a = __builtin_amdgcn_mfma_f32_16x16x32_bf16(aH, bL, a, 0, 0, 0);
            acc1[ct] = a;
        }
        __builtin_amdgcn_s_setprio(0);
        {   // head
            bf8 pH = *(const bf8*)&wbH[72][l * 8];
            bf8 pL = *(const bf8*)&wbL[72][l * 8];
            f4 p = (f4){0.f, 0.f, 0.f, 0.f};
            __builtin_amdgcn_s_setprio(1);
            p = __builtin_amdgcn_mfma_f32_16x16x32_bf16(aH, pH, p, 0, 0, 0);
            p = __builtin_amdgcn_mfma_f32_16x16x32_bf16(aL, pH, p, 0, 0, 0);
            p = __builtin_amdgcn_mfma_f32_16x16x32_bf16(aH, pL, p, 0, 0, 0);
            __builtin_amdgcn_s_setprio(0);
            if (lr < 10) {
                float bpv = bp[lr];
#pragma unroll
                for (int rg = 0; rg < 4; ++rg) {
                    int g = row0 + wrow + lg * 4 + rg;
                    if (g < n) out[(size_t)g * 170 + 32 + lr] = p[rg] + bpv;
                }
            }
        }

        // ---- stage 2 ----
        f4 acc2[8];
#pragma unroll
        for (int ct = 0; ct < 8; ++ct) acc2[ct] = (f4){0.f, 0.f, 0.f, 0.f};
#pragma unroll
        for (int kt = 0; kt < 4; ++kt) {
            u32 w[8];
            {   // slice 0
                int ct = kt * 2;
                float bv = bd1[ct * 16 + lr];
                float v0 = fmaxf(acc1[ct][0] + bv, 0.f), v1 = fmaxf(acc1[ct][1] + bv, 0.f);
                float v2 = fmaxf(acc1[ct][2] + bv, 0.f), v3 = fmaxf(acc1[ct][3] + bv, 0.f);
                u32 hp01 = cvtpk(v0, v1), hp23 = cvtpk(v2, v3);
                u32 lp01 = cvtpk(v0 - bf2f((u16)hp01), v1 - bf2f((u16)(hp01 >> 16)));
                u32 lp23 = cvtpk(v2 - bf2f((u16)hp23), v3 - bf2f((u16)(hp23 >> 16)));
                scr[wrow + lg * 4 + 0][lr] = (hp01 & 0xffffu) | (lp01 << 16);
                scr[wrow + lg * 4 + 1][lr] = (hp01 >> 16) | (lp01 & 0xffff0000u);
                scr[wrow + lg * 4 + 2][lr] = (hp23 & 0xffffu) | (lp23 << 16);
                scr[wrow + lg * 4 + 3][lr] = (hp23 >> 16) | (lp23 & 0xffff0000u);
            }
            if (lg < 2) {
                *(uint4*)&w[0] = *(const uint4*)&scr[wrow + lr][lg * 8];
                *(uint4*)&w[4] = *(const uint4*)&scr[wrow + lr][lg * 8 + 4];
            }
            {   // slice 1
                int ct = kt * 2 + 1;
                float bv = bd1[ct * 16 + lr];
                float v0 = fmaxf(acc1[ct][0] + bv, 0.f), v1 = fmaxf(acc1[ct][1] + bv, 0.f);
                float v2 = fmaxf(acc1[ct][2] + bv, 0.f), v3 = fmaxf(acc1[ct][3] + bv, 0.f);
                u32 hp01 = cvtpk(v0, v1), hp23 = cvtpk(v2, v3);
                u32 lp01 = cvtpk(v0 - bf2f((u16)hp01), v1 - bf2f((u16)(hp01 >> 16)));
                u32 lp23 = cvtpk(v2 - bf2f((u16)hp23), v3 - bf2f((u16)(hp23 >> 16)));
                scr[wrow + lg * 4 + 0][lr] = (hp01 & 0xffffu) | (lp01 << 16);
                scr[wrow + lg * 4 + 1][lr] = (hp01 >> 16) | (lp01 & 0xffff0000u);
                scr[wrow + lg * 4 + 2][lr] = (hp23 & 0xffffu) | (lp23 << 16);
                scr[wrow + lg * 4 + 3][lr] = (hp23 >> 16) | (lp23 & 0xffff0000u);
            }
            if (lg >= 2) {
                *(uint4*)&w[0] = *(const uint4*)&scr[wrow + lr][(lg - 2) * 8];
                *(uint4*)&w[4] = *(const uint4*)&scr[wrow + lr][(lg - 2) * 8 + 4];
            }
            bf8 a2H, a2L;
#pragma unroll
            for (int j = 0; j < 8; ++j) {
                ((u16*)&a2H)[j] = (u16)(w[j] & 0xffffu);
                ((u16*)&a2L)[j] = (u16)(w[j] >> 16);
            }
            __builtin_amdgcn_s_setprio(1);
#pragma unroll
            for (int ct = 0; ct < 8; ++ct) {
                bf8 bH = *(const bf8*)&wbH[8 + kt * 8 + ct][l * 8];
                bf8 bL = *(const bf8*)&wbL[8 + kt * 8 + ct][l * 8];
                acc2[ct] = __builtin_amdgcn_mfma_f32_16x16x32_bf16(a2H, bH, acc2[ct], 0, 0, 0);
                acc2[ct] = __builtin_amdgcn_mfma_f32_16x16x32_bf16(a2L, bH, acc2[ct], 0, 0, 0);
                acc2[ct] = __builtin_amdgcn_mfma_f32_16x16x32_bf16(a2H, bL, acc2[ct], 0, 0, 0);
            }
            __builtin_amdgcn_s_setprio(0);
        }

        // ---- stage 3 ----
        f4 acc3[8];
#pragma unroll
        for (int ct = 0; ct < 8; ++ct) acc3[ct] = (f4){0.f, 0.f, 0.f, 0.f};
#pragma unroll
        for (int kt = 0; kt < 4; ++kt) {
            u32 w[8];
            {
                int ct = kt * 2;
                float bv = bd2[ct * 16 + lr];
                float v0 = fmaxf(acc2[ct][0] + bv, 0.f), v1 = fmaxf(acc2[ct][1] + bv, 0.f);
                float v2 = fmaxf(acc2[ct][2] + bv, 0.f), v3 = fmaxf(acc2[ct][3] + bv, 0.f);
                u32 hp01 = cvtpk(v0, v1), hp23 = cvtpk(v2, v3);
                u32 lp01 = cvtpk(v0 - bf2f((u16)hp01), v1 - bf2f((u16)(hp01 >> 16)));
                u32 lp23 = cvtpk(v2 - bf2f((u16)hp23), v3 - bf2f((u16)(hp23 >> 16)));
                scr[wrow + lg * 4 + 0][lr] = (hp01 & 0xffffu) | (lp01 << 16);
                scr[wrow + lg * 4 + 1][lr] = (hp01 >> 16) | (lp01 & 0xffff0000u);
                scr[wrow + lg * 4 + 2][lr] = (hp23 & 0xffffu) | (lp23 << 16);
                scr[wrow + lg * 4 + 3][lr] = (hp23 >> 16) | (lp23 & 0xffff0000u);
            }
            if (lg < 2) {
                *(uint4*)&w[0] = *(const uint4*)&scr[wrow + lr][lg * 8];
                *(uint4*)&w[4] = *(const uint4*)&scr[wrow + lr][lg * 8 + 4];
            }
            {
                int ct = kt * 2 + 1;
                float bv = bd2[ct * 16 + lr];
                float v0 = fmaxf(acc2[ct][0] + bv, 0.f), v1 = fmaxf(acc2[ct][1] + bv, 0.f);
                float v2 = fmaxf(acc2[ct][2] + bv, 0.f), v3 = fmaxf(acc2[ct][3] + bv, 0.f);
                u32 hp01 = cvtpk(v0, v1), hp23 = cvtpk(v2, v3);
                u32 lp01 = cvtpk(v0 - bf2f((u16)hp01), v1 - bf2f((u16)(hp01 >> 16)));
                u32 lp23 = cvtpk(v2 - bf2f((u16)hp23), v3 - bf2f((u16)(hp23 >> 16)));
                scr[wrow + lg * 4 + 0][lr] = (hp01 & 0xffffu) | (lp01 << 16);
                scr[wrow + lg * 4 + 1][lr] = (hp01 >> 16) | (lp01 & 0xffff0000u);
                scr[wrow + lg * 4 + 2][lr] = (hp23 & 0xffffu) | (lp23 << 16);
                scr[wrow + lg * 4 + 3][lr] = (hp23 >> 16) | (lp23 & 0xffff0000u);
            }
            if (lg >= 2) {
                *(uint4*)&w[0] = *(const uint4*)&scr[wrow + lr][(lg - 2) * 8];
                *(uint4*)&w[4] = *(const uint4*)&scr[wrow + lr][(lg - 2) * 8 + 4];
            }
            bf8 a3H, a3L;
#pragma unroll
            for (int j = 0; j < 8; ++j) {
                ((u16*)&a3H)[j] = (u16)(w[j] & 0xffffu);
                ((u16*)&a3L)[j] = (u16)(w[j] >> 16);
            }
            __builtin_amdgcn_s_setprio(1);
#pragma unroll
            for (int ct = 0; ct < 8; ++ct) {
                bf8 bH = *(const bf8*)&wbH[40 + kt * 8 + ct][l * 8];
                bf8 bL = *(const bf8*)&wbL[40 + kt * 8 + ct][l * 8];
                acc3[ct] = __builtin_amdgcn_mfma_f32_16x16x32_bf16(a3H, bH, acc3[ct], 0, 0, 0);
                acc3[ct] = __builtin_amdgcn_mfma_f32_16x16x32_bf16(a3L, bH, acc3[ct], 0, 0, 0);
                acc3[ct] = __builtin_amdgcn_mfma_f32_16x16x32_bf16(a3H, bL, acc3[ct], 0, 0, 0);
            }
            __builtin_amdgcn_s_setprio(0);
        }

        // ---- epilogue: softplus -> out[:,42:170) ----
#pragma unroll
        for (int ct = 0; ct < 8; ++ct) {
            float bv = bd3[ct * 16 + lr];
#pragma unroll
            for (int rg = 0; rg < 4; ++rg) {
                int g = row0 + wrow + lg * 4 + rg;
                if (g < n) {
                    float v = acc3[ct][rg] + bv;
                    v = fmaxf(v, 0.f) + __logf(1.f + __expf(-fabsf(v)));
                    out[(size_t)g * 170 + 42 + ct * 16 + lr] = v;
                }
            }
        }
    }
}

// ---------------- launch ----------------

extern "C" void kernel_launch(void* const* d_in, const int* in_sizes, int n_in,
                              void* d_out, int out_size, void* d_ws, size_t ws_size,
                              hipStream_t stream) {
    const float* raw_x = (const float*)d_in[0];
    const int*   ei    = (const int*)d_in[1];
    const float* W1 = (const float*)d_in[2];  const float* b1 = (const float*)d_in[3];
    const float* W2 = (const float*)d_in[4];  const float* b2 = (const float*)d_in[5];
    const float* Wp = (const float*)d_in[6];  const float* bp = (const float*)d_in[7];
    const float* Wd1 = (const float*)d_in[8]; const float* bd1 = (const float*)d_in[9];
    const float* Wd2 = (const float*)d_in[10]; const float* bd2 = (const float*)d_in[11];
    const float* Wd3 = (const float*)d_in[12]; const float* bd3 = (const float*)d_in[13];

    const int n = in_sizes[0] / 128;   // 50000
    const int E = in_sizes[1] / 2;     // 800000
    const int* row = ei;        // source
    const int* col = ei + E;    // target

    float* out = (float*)d_out;

    const int nwg  = (E + CHUNK - 1) / CHUNK;   // 391
    const int nbuk = (n + 63) >> 6;             // 782

    // workspace layout (aligned)
    char* ws = (char*)d_ws;
    auto alloc = [&](size_t bytes) {
        ws = (char*)(((uintptr_t)ws + 255) & ~(uintptr_t)255);
        char* p = ws; ws += bytes; return (void*)p;
    };
    float* dinv   = (float*)alloc((size_t)n * 4);
    int*   rowptr = (int*)alloc((size_t)(n + 4) * 4);
    int*   boff   = (int*)alloc((size_t)(nbuk + 4) * 4);
    int*   bsum   = (int*)alloc((size_t)nbuk * 4);
    int*   M      = (int*)alloc((size_t)nbuk * nwg * 4);
    int*   csrc   = (int*)alloc((size_t)E * 4);
    int2*  ebuf   = (int2*)alloc((size_t)E * 8);
    u16*   hs1b   = (u16*)alloc((size_t)n * 64 * 2);     // bf16 hs1
    u16*   hs2b   = (u16*)alloc((size_t)n * 32 * 2);     // bf16 hs2
    u16*   wswHi  = (u16*)alloc((size_t)89 * 512 * 2);
    u16*   wswLo  = (u16*)alloc((size_t)89 * 512 * 2);

    const int BS = 256;
    auto blocks = [](long long work, int bs) { return (unsigned)((work + bs - 1) / bs); };
    const int ntiles1 = (n + 127) / 128;             // 391 (gemm1 + decoder tiles)

    // ---- graph structure: bucketed counting sort (zero global atomics) ----
    bucket_hist<<<nwg, 256, 0, stream>>>(col, M, E, nbuk, nwg);
    col_scan_wave<<<blocks((long long)nbuk * 64, BS), BS, 0, stream>>>(M, bsum, nbuk, nwg);
    bucket_scan<<<1, 1024, 0, stream>>>(bsum, boff, rowptr, nbuk, n, E);
    bucket_scatter<<<nwg, 256, 0, stream>>>(row, col, M, boff, ebuf, E, nwg);
    bucket_finalize<<<nbuk, 256, 0, stream>>>(ebuf, boff, rowptr, csrc, dinv, n);

    // ---- weight swizzle (independent; includes W1 tiles 73..88) ----
    wswz_kernel<<<89, 64, 0, stream>>>(Wd1, Wd2, Wd3, Wp, W1, wswHi, wswLo);

    // ---- GCN layer 1 via MFMA: raw_x[128] -> 64 (bf16 hs1) ----
    gemm1_mfma<<<391, 512, 0, stream>>>(raw_x, wswHi, wswLo, dinv, hs1b, n, ntiles1);

    // ---- fused agg1 + layer-2 GEMM: hs1 -> hs2 (bf16), x1 never materialized ----
    agg1_gemm2<<<blocks((long long)n * 8, BS), BS, 0, stream>>>(
        rowptr, csrc, hs1b, dinv, b1, W2, hs2b, n);

    // ---- layer-2 aggregation: hs2 -> emb (out[:,0:32)) ----
    agg_finalize_bf16<32, false><<<blocks((long long)n * 4, BS), BS, 0, stream>>>(
        rowptr, csrc, hs2b, dinv, b2, out, n, 170, 0);

    // ---- fully-fused decoder: 8 waves/block, weights resident in LDS ----
    dec_fused<<<256, 512, 0, stream>>>(out, wswHi, wswLo, bp, bd1, bd2, bd3, out, n, ntiles1);
}

// Round 26
// 124.036 us; speedup vs baseline: 1.0124x; 1.0124x over previous
//
#include <hip/hip_runtime.h>
#include <hip/hip_bf16.h>
#include <math.h>

typedef unsigned short u16;
typedef unsigned int u32;
typedef __attribute__((ext_vector_type(8))) short bf8;   // 8 bf16 = 4 VGPR
typedef __attribute__((ext_vector_type(4))) float f4;    // 4 f32 acc

__device__ __forceinline__ u16 bfhi(float x) {
    u32 u = __float_as_uint(x);
    u32 r = u + 0x7FFFu + ((u >> 16) & 1u);   // RNE
    return (u16)(r >> 16);
}
__device__ __forceinline__ float bf2f(u16 h) { return __uint_as_float(((u32)h) << 16); }
// packed RNE f32x2 -> bf16x2 (compiler emits v_cvt_pk_bf16_f32)
__device__ __forceinline__ u32 cvtpk(float a, float b) {
    __hip_bfloat162 h = __float22bfloat162_rn(make_float2(a, b));
    u32 r;
    __builtin_memcpy(&r, &h, 4);
    return r;
}

// ================= graph build: zero-global-atomic bucketed CSR =================
// bucket = col >> 6. CH = 2048 edges per workgroup -> nwg = 391 blocks (full CU use).

#define CHUNK 2048

__global__ __launch_bounds__(256) void bucket_hist(const int* __restrict__ col,
                                                   int* __restrict__ M, int E, int nbuk, int nwg) {
    __shared__ int h[1024];
    const int tid = threadIdx.x;
    for (int i = tid; i < 1024; i += 256) h[i] = 0;
    __syncthreads();
    int base = blockIdx.x * CHUNK;
    for (int i = tid; i < CHUNK; i += 256) {
        int e = base + i;
        if (e < E) atomicAdd(&h[col[e] >> 6], 1);   // LDS atomic
    }
    __syncthreads();
    for (int b = tid; b < nbuk; b += 256) M[b * nwg + blockIdx.x] = h[b];
}

// one 64-lane wave per bucket: shfl inclusive scan over nwg chunk-counts (carry-chained)
__global__ __launch_bounds__(256) void col_scan_wave(int* __restrict__ M, int* __restrict__ bsum,
                                                     int nbuk, int nwg) {
    int wave = (blockIdx.x * blockDim.x + threadIdx.x) >> 6;
    int lane = threadIdx.x & 63;
    if (wave >= nbuk) return;
    int* Mb = M + (size_t)wave * nwg;
    int carry = 0;
    for (int base = 0; base < nwg; base += 64) {
        int w = base + lane;
        int v = (w < nwg) ? Mb[w] : 0;
        int x = v;
        for (int off = 1; off < 64; off <<= 1) {
            int y = __shfl_up(x, off);
            if (lane >= off) x += y;
        }
        if (w < nwg) Mb[w] = carry + x - v;   // exclusive
        carry += __shfl(x, 63);
    }
    if (lane == 0) bsum[wave] = carry;
}

__global__ void bucket_scan(const int* __restrict__ bsum, int* __restrict__ boff,
                            int* __restrict__ rowptr, int nbuk, int n, int E) {
    __shared__ int sh[1024];
    const int tid = threadIdx.x;
    int v = (tid < nbuk) ? bsum[tid] : 0;
    sh[tid] = v; __syncthreads();
    for (int off = 1; off < 1024; off <<= 1) {
        int x = sh[tid];
        int w = (tid >= off) ? sh[tid - off] : 0;
        __syncthreads();
        sh[tid] = x + w;
        __syncthreads();
    }
    if (tid < nbuk) boff[tid] = sh[tid] - v;
    if (tid == 0) { boff[nbuk] = E; rowptr[n] = E; }
}

__global__ __launch_bounds__(256) void bucket_scatter(const int* __restrict__ row,
                                                      const int* __restrict__ col,
                                                      const int* __restrict__ M,
                                                      const int* __restrict__ boff,
                                                      int2* __restrict__ ebuf, int E, int nwg) {
    __shared__ int h[1024];
    const int tid = threadIdx.x;
    for (int i = tid; i < 1024; i += 256) h[i] = 0;
    __syncthreads();
    int base = blockIdx.x * CHUNK;
    for (int i = tid; i < CHUNK; i += 256) {
        int e = base + i;
        if (e < E) {
            int c = col[e], b = c >> 6;
            int rank = atomicAdd(&h[b], 1);  // LDS
            int slot = boff[b] + M[b * nwg + blockIdx.x] + rank;
            ebuf[slot] = make_int2(c, row[e]);
        }
    }
}

__global__ __launch_bounds__(256) void bucket_finalize(const int2* __restrict__ ebuf,
                                                       const int* __restrict__ boff,
                                                       int* __restrict__ rowptr,
                                                       int* __restrict__ csrc,
                                                       float* __restrict__ dinv, int n) {
    __shared__ int h[64];
    __shared__ int curs[64];
    const int b = blockIdx.x, tid = threadIdx.x;
    const int n0 = b << 6;
    const int beg = boff[b], end = boff[b + 1];
    if (tid < 64) h[tid] = 0;
    __syncthreads();
    for (int i = beg + tid; i < end; i += 256) atomicAdd(&h[ebuf[i].x & 63], 1);
    __syncthreads();
    if (tid < 64) {                    // first wave: 64-lane shfl scan
        int cnt = h[tid];
        int v = cnt;
        for (int off = 1; off < 64; off <<= 1) {
            int w = __shfl_up(v, off);
            if (tid >= off) v += w;
        }
        int cursor = beg + v - cnt;    // exclusive
        curs[tid] = cursor;
        int node = n0 + tid;
        if (node < n) {
            rowptr[node] = cursor;
            dinv[node] = rsqrtf((float)(cnt + 1));   // +1 self loop
        }
    }
    __syncthreads();
    for (int i = beg + tid; i < end; i += 256) {
        int2 e = ebuf[i];
        int slot = atomicAdd(&curs[e.x & 63], 1);    // LDS
        csrc[slot] = e.y;
    }
}

// ------- fused agg1 + layer-2 GEMM -------
__global__ __launch_bounds__(256) void agg1_gemm2(
    const int* __restrict__ rowptr, const int* __restrict__ csrc,
    const u16* __restrict__ hs, const float* __restrict__ dinv,
    const float* __restrict__ b1, const float* __restrict__ W2,
    u16* __restrict__ hs2, int n) {
    __shared__ float w2s[64][33];   // pad 33
    const int tid = threadIdx.x;
    for (int i = tid; i < 64 * 32; i += 256) w2s[i >> 5][i & 31] = W2[i];
    __syncthreads();

    int gid = blockIdx.x * blockDim.x + tid;
    int node = gid >> 3, lane = gid & 7;
    if (node >= n) return;
    int f0 = lane * 8;
    int beg = rowptr[node], end = rowptr[node + 1];
    float s[8] = {0.f, 0.f, 0.f, 0.f, 0.f, 0.f, 0.f, 0.f};
    auto acc8 = [&](uint4 v) {
        u32 a0 = v.x, a1 = v.y, a2 = v.z, a3 = v.w;
        s[0] += bf2f((u16)a0); s[1] += bf2f((u16)(a0 >> 16));
        s[2] += bf2f((u16)a1); s[3] += bf2f((u16)(a1 >> 16));
        s[4] += bf2f((u16)a2); s[5] += bf2f((u16)(a2 >> 16));
        s[6] += bf2f((u16)a3); s[7] += bf2f((u16)(a3 >> 16));
    };
    int j = beg;
    for (; j + 3 < end; j += 4) {
        int s0 = csrc[j], s1 = csrc[j + 1], s2 = csrc[j + 2], s3 = csrc[j + 3];
        uint4 v0 = *(const uint4*)&hs[(size_t)s0 * 64 + f0];
        uint4 v1 = *(const uint4*)&hs[(size_t)s1 * 64 + f0];
        uint4 v2 = *(const uint4*)&hs[(size_t)s2 * 64 + f0];
        uint4 v3 = *(const uint4*)&hs[(size_t)s3 * 64 + f0];
        acc8(v0); acc8(v1); acc8(v2); acc8(v3);
    }
    for (; j < end; ++j) acc8(*(const uint4*)&hs[(size_t)csrc[j] * 64 + f0]);
    acc8(*(const uint4*)&hs[(size_t)node * 64 + f0]);   // self loop

    float di = dinv[node];
    float r[8];
#pragma unroll
    for (int c = 0; c < 8; ++c) r[c] = fmaxf(di * s[c] + b1[f0 + c], 0.f);

    float part[32];
#pragma unroll
    for (int c = 0; c < 32; ++c) part[c] = 0.f;
#pragma unroll
    for (int jj = 0; jj < 8; ++jj) {
        float rv = r[jj];
#pragma unroll
        for (int c = 0; c < 32; ++c) part[c] = fmaf(rv, w2s[f0 + jj][c], part[c]);
    }
#pragma unroll
    for (int m = 1; m < 8; m <<= 1) {
#pragma unroll
        for (int c = 0; c < 32; ++c) part[c] += __shfl_xor(part[c], m);
    }
    int c0 = lane * 4;
    u32 p0 = cvtpk(part[c0] * di, part[c0 + 1] * di);
    u32 p1 = cvtpk(part[c0 + 2] * di, part[c0 + 3] * di);
    *(uint2*)&hs2[(size_t)node * 32 + c0] = make_uint2(p0, p1);
}

// ------- CSR gather aggregation from bf16 rows (layer-2 agg -> emb) -------
template<int F, bool OV>
__global__ void agg_finalize_bf16(const int* __restrict__ rowptr, const int* __restrict__ csrc,
                                  const u16* __restrict__ hs, const float* __restrict__ dinv,
                                  const float* __restrict__ b, float* __restrict__ out,
                                  int n, int ostride, int col0) {
    constexpr int L = F / 8;                 // lanes per node
    int tid = blockIdx.x * blockDim.x + threadIdx.x;
    int node = tid / L, lane = tid % L;
    if (node >= n) return;
    int f0 = lane * 8;                       // u16 index
    int beg = rowptr[node], end = rowptr[node + 1];
    float s[8] = {0.f, 0.f, 0.f, 0.f, 0.f, 0.f, 0.f, 0.f};
    auto acc8 = [&](uint4 v) {
        u32 a0 = v.x, a1 = v.y, a2 = v.z, a3 = v.w;
        s[0] += bf2f((u16)a0); s[1] += bf2f((u16)(a0 >> 16));
        s[2] += bf2f((u16)a1); s[3] += bf2f((u16)(a1 >> 16));
        s[4] += bf2f((u16)a2); s[5] += bf2f((u16)(a2 >> 16));
        s[6] += bf2f((u16)a3); s[7] += bf2f((u16)(a3 >> 16));
    };
    int j = beg;
    for (; j + 3 < end; j += 4) {
        int s0 = csrc[j], s1 = csrc[j + 1], s2 = csrc[j + 2], s3 = csrc[j + 3];
        uint4 v0 = *(const uint4*)&hs[(size_t)s0 * F + f0];
        uint4 v1 = *(const uint4*)&hs[(size_t)s1 * F + f0];
        uint4 v2 = *(const uint4*)&hs[(size_t)s2 * F + f0];
        uint4 v3 = *(const uint4*)&hs[(size_t)s3 * F + f0];
        acc8(v0); acc8(v1); acc8(v2); acc8(v3);
    }
    for (; j < end; ++j) acc8(*(const uint4*)&hs[(size_t)csrc[j] * F + f0]);
    acc8(*(const uint4*)&hs[(size_t)node * F + f0]);   // self loop
    float di = dinv[node];
    float r[8];
#pragma unroll
    for (int c = 0; c < 8; ++c) r[c] = fmaxf(di * s[c] + b[f0 + c], 0.f);
    float* op = &out[(size_t)node * ostride + col0 + f0];
    if (OV) {
        *(float4*)op = make_float4(r[0], r[1], r[2], r[3]);
        *(float4*)(op + 4) = make_float4(r[4], r[5], r[6], r[7]);
    } else {
#pragma unroll
        for (int c = 0; c < 8; ++c) op[c] = r[c];
    }
}

// ---------------- weight pre-swizzle into MFMA B-fragment order ----------------
// tiles: 0..7 Wd1(32x128), 8..39 Wd2(128x128), 40..71 Wd3(128x128), 72 Wp(32x10 pad16),
//        73..88 W1(128x64)
__global__ void wswz_kernel(const float* __restrict__ Wd1, const float* __restrict__ Wd2,
                            const float* __restrict__ Wd3, const float* __restrict__ Wp,
                            const float* __restrict__ W1,
                            u16* __restrict__ whi, u16* __restrict__ wlo) {
    int t = blockIdx.x, l = threadIdx.x;   // 89 blocks x 64 threads
    const float* W; int C, kt, ct;
    if (t < 8)       { W = Wd1; C = 128; kt = 0;            ct = t; }
    else if (t < 40) { W = Wd2; C = 128; kt = (t - 8) >> 3;  ct = (t - 8) & 7; }
    else if (t < 72) { W = Wd3; C = 128; kt = (t - 40) >> 3; ct = (t - 40) & 7; }
    else if (t < 73) { W = Wp;  C = 10;  kt = 0;            ct = 0; }
    else             { W = W1;  C = 64;  kt = (t - 73) >> 2; ct = (t - 73) & 3; }
    int kbase = kt * 32 + (l >> 4) * 8;
    int c = ct * 16 + (l & 15);
    size_t base = (size_t)t * 512 + (size_t)l * 8;
#pragma unroll
    for (int j = 0; j < 8; ++j) {
        float v = (c < C) ? W[(size_t)(kbase + j) * C + c] : 0.f;
        u16 h = bfhi(v);
        whi[base + j] = (u16)h;
        wlo[base + j] = bfhi(v - bf2f(h));
    }
}

// ---------------- GCN layer-1 GEMM via split-bf16 MFMA, bf16 output ----------------
__global__ __launch_bounds__(512) void gemm1_mfma(
    const float* __restrict__ x, const u16* __restrict__ whi, const u16* __restrict__ wlo,
    const float* __restrict__ dinv, u16* __restrict__ outp, int n, int ntiles) {
    __shared__ __align__(16) u16 wH[16][512], wL[16][512];   // 32 KB

    const int tid = threadIdx.x;
    const int l = tid & 63, wv = tid >> 6;
    const int lr = l & 15, lg = l >> 4;
    const int wrow = wv * 16;

    for (int i = tid; i < 16 * 64; i += 512) {
        ((int4*)wH)[i] = ((const int4*)(whi + 73 * 512))[i];
        ((int4*)wL)[i] = ((const int4*)(wlo + 73 * 512))[i];
    }
    __syncthreads();

    for (int t = blockIdx.x; t < ntiles; t += gridDim.x) {
        const int row0 = t * 128;
        int arow = row0 + wrow + lr; if (arow >= n) arow = n - 1;
        const float* src = &x[(size_t)arow * 128];

        f4 acc[4];
#pragma unroll
        for (int ct = 0; ct < 4; ++ct) acc[ct] = (f4){0.f, 0.f, 0.f, 0.f};
#pragma unroll
        for (int kt = 0; kt < 4; ++kt) {
            const float* s = src + kt * 32 + lg * 8;
            float4 v0 = *(const float4*)s, v1 = *(const float4*)(s + 4);
            float xs[8] = {v0.x, v0.y, v0.z, v0.w, v1.x, v1.y, v1.z, v1.w};
            bf8 aH, aL;
#pragma unroll
            for (int j = 0; j < 8; j += 2) {
                u32 hp = cvtpk(xs[j], xs[j + 1]);
                ((u32*)&aH)[j >> 1] = hp;
                float l0 = xs[j] - bf2f((u16)hp);
                float l1 = xs[j + 1] - bf2f((u16)(hp >> 16));
                ((u32*)&aL)[j >> 1] = cvtpk(l0, l1);
            }
#pragma unroll
            for (int ct = 0; ct < 4; ++ct) {
                bf8 bH = *(const bf8*)&wH[kt * 4 + ct][l * 8];
                bf8 bL = *(const bf8*)&wL[kt * 4 + ct][l * 8];
                acc[ct] = __builtin_amdgcn_mfma_f32_16x16x32_bf16(aH, bH, acc[ct], 0, 0, 0);
                acc[ct] = __builtin_amdgcn_mfma_f32_16x16x32_bf16(aL, bH, acc[ct], 0, 0, 0);
                acc[ct] = __builtin_amdgcn_mfma_f32_16x16x32_bf16(aH, bL, acc[ct], 0, 0, 0);
            }
        }
#pragma unroll
        for (int rg = 0; rg < 4; ++rg) {
            int g = row0 + wrow + lg * 4 + rg;
            if (g < n) {
                float di = dinv[g];
                u16* op = &outp[(size_t)g * 64 + lr];
#pragma unroll
                for (int ct = 0; ct < 4; ++ct) op[ct * 16] = bfhi(acc[ct][rg] * di);
            }
        }
    }
}

// ---------------- fully-fused MFMA decoder: 8 waves, 128-row tiles ----------------
__global__ __launch_bounds__(512, 1) void dec_fused(
    const float* __restrict__ obuf,
    const u16* __restrict__ whi, const u16* __restrict__ wlo,
    const float* __restrict__ bp, const float* __restrict__ bd1,
    const float* __restrict__ bd2, const float* __restrict__ bd3,
    float* __restrict__ out, int n, int ntiles) {
    __shared__ __align__(16) u16 wbH[73][512];   // 74752 B
    __shared__ __align__(16) u16 wbL[73][512];   // 74752 B
    __shared__ __align__(16) u32 scr[128][20];   // 10240 B

    const int tid = threadIdx.x;
    const int l = tid & 63, wv = tid >> 6;       // 8 waves
    const int lr = l & 15, lg = l >> 4;
    const int wrow = wv * 16;

    for (int i = tid; i < 73 * 64; i += 512) {
        ((int4*)wbH)[i] = ((const int4*)whi)[i];
        ((int4*)wbL)[i] = ((const int4*)wlo)[i];
    }
    __syncthreads();

    for (int t = blockIdx.x; t < ntiles; t += gridDim.x) {
        const int row0 = t * 128;
        int arow = row0 + wrow + lr; if (arow >= n) arow = n - 1;

        const float* src = &obuf[(size_t)arow * 170 + lg * 8];
        bf8 aH, aL;
#pragma unroll
        for (int i = 0; i < 8; i += 2) {
            float2 v = *(const float2*)(src + i);
            u32 hp = cvtpk(v.x, v.y);
            ((u32*)&aH)[i >> 1] = hp;
            float l0 = v.x - bf2f((u16)hp);
            float l1 = v.y - bf2f((u16)(hp >> 16));
            ((u32*)&aL)[i >> 1] = cvtpk(l0, l1);
        }

        // ---- stage 1 ----
        f4 acc1[8];
#pragma unroll
        for (int ct = 0; ct < 8; ++ct) {
            bf8 bH = *(const bf8*)&wbH[ct][l * 8];
            bf8 bL = *(const bf8*)&wbL[ct][l * 8];
            f4 a = (f4){0.f, 0.f, 0.f, 0.f};
            a = __builtin_amdgcn_mfma_f32_16x16x32_bf16(aH, bH, a, 0, 0, 0);
            a = __builtin_amdgcn_mfma_f32_16x16x32_bf16(aL, bH, a, 0, 0, 0);
            a = __builtin_amdgcn_mfma_f32_16x16x32_bf16(aH, bL, a, 0, 0, 0);
            acc1[ct] = a;
        }
        {   // head
            bf8 pH = *(const bf8*)&wbH[72][l * 8];
            bf8 pL = *(const bf8*)&wbL[72][l * 8];
            f4 p = (f4){0.f, 0.f, 0.f, 0.f};
            p = __builtin_amdgcn_mfma_f32_16x16x32_bf16(aH, pH, p, 0, 0, 0);
            p = __builtin_amdgcn_mfma_f32_16x16x32_bf16(aL, pH, p, 0, 0, 0);
            p = __builtin_amdgcn_mfma_f32_16x16x32_bf16(aH, pL, p, 0, 0, 0);
            if (lr < 10) {
                float bpv = bp[lr];
#pragma unroll
                for (int rg = 0; rg < 4; ++rg) {
                    int g = row0 + wrow + lg * 4 + rg;
                    if (g < n) out[(size_t)g * 170 + 32 + lr] = p[rg] + bpv;
                }
            }
        }

        // ---- stage 2 ----
        f4 acc2[8];
#pragma unroll
        for (int ct = 0; ct < 8; ++ct) acc2[ct] = (f4){0.f, 0.f, 0.f, 0.f};
#pragma unroll
        for (int kt = 0; kt < 4; ++kt) {
            u32 w[8];
            {   // slice 0
                int ct = kt * 2;
                float bv = bd1[ct * 16 + lr];
                float v0 = fmaxf(acc1[ct][0] + bv, 0.f), v1 = fmaxf(acc1[ct][1] + bv, 0.f);
                float v2 = fmaxf(acc1[ct][2] + bv, 0.f), v3 = fmaxf(acc1[ct][3] + bv, 0.f);
                u32 hp01 = cvtpk(v0, v1), hp23 = cvtpk(v2, v3);
                u32 lp01 = cvtpk(v0 - bf2f((u16)hp01), v1 - bf2f((u16)(hp01 >> 16)));
                u32 lp23 = cvtpk(v2 - bf2f((u16)hp23), v3 - bf2f((u16)(hp23 >> 16)));
                scr[wrow + lg * 4 + 0][lr] = (hp01 & 0xffffu) | (lp01 << 16);
                scr[wrow + lg * 4 + 1][lr] = (hp01 >> 16) | (lp01 & 0xffff0000u);
                scr[wrow + lg * 4 + 2][lr] = (hp23 & 0xffffu) | (lp23 << 16);
                scr[wrow + lg * 4 + 3][lr] = (hp23 >> 16) | (lp23 & 0xffff0000u);
            }
            if (lg < 2) {
                *(uint4*)&w[0] = *(const uint4*)&scr[wrow + lr][lg * 8];
                *(uint4*)&w[4] = *(const uint4*)&scr[wrow + lr][lg * 8 + 4];
            }
            {   // slice 1
                int ct = kt * 2 + 1;
                float bv = bd1[ct * 16 + lr];
                float v0 = fmaxf(acc1[ct][0] + bv, 0.f), v1 = fmaxf(acc1[ct][1] + bv, 0.f);
                float v2 = fmaxf(acc1[ct][2] + bv, 0.f), v3 = fmaxf(acc1[ct][3] + bv, 0.f);
                u32 hp01 = cvtpk(v0, v1), hp23 = cvtpk(v2, v3);
                u32 lp01 = cvtpk(v0 - bf2f((u16)hp01), v1 - bf2f((u16)(hp01 >> 16)));
                u32 lp23 = cvtpk(v2 - bf2f((u16)hp23), v3 - bf2f((u16)(hp23 >> 16)));
                scr[wrow + lg * 4 + 0][lr] = (hp01 & 0xffffu) | (lp01 << 16);
                scr[wrow + lg * 4 + 1][lr] = (hp01 >> 16) | (lp01 & 0xffff0000u);
                scr[wrow + lg * 4 + 2][lr] = (hp23 & 0xffffu) | (lp23 << 16);
                scr[wrow + lg * 4 + 3][lr] = (hp23 >> 16) | (lp23 & 0xffff0000u);
            }
            if (lg >= 2) {
                *(uint4*)&w[0] = *(const uint4*)&scr[wrow + lr][(lg - 2) * 8];
                *(uint4*)&w[4] = *(const uint4*)&scr[wrow + lr][(lg - 2) * 8 + 4];
            }
            bf8 a2H, a2L;
#pragma unroll
            for (int j = 0; j < 8; ++j) {
                ((u16*)&a2H)[j] = (u16)(w[j] & 0xffffu);
                ((u16*)&a2L)[j] = (u16)(w[j] >> 16);
            }
#pragma unroll
            for (int ct = 0; ct < 8; ++ct) {
                bf8 bH = *(const bf8*)&wbH[8 + kt * 8 + ct][l * 8];
                bf8 bL = *(const bf8*)&wbL[8 + kt * 8 + ct][l * 8];
                acc2[ct] = __builtin_amdgcn_mfma_f32_16x16x32_bf16(a2H, bH, acc2[ct], 0, 0, 0);
                acc2[ct] = __builtin_amdgcn_mfma_f32_16x16x32_bf16(a2L, bH, acc2[ct], 0, 0, 0);
                acc2[ct] = __builtin_amdgcn_mfma_f32_16x16x32_bf16(a2H, bL, acc2[ct], 0, 0, 0);
            }
        }

        // ---- stage 3 ----
        f4 acc3[8];
#pragma unroll
        for (int ct = 0; ct < 8; ++ct) acc3[ct] = (f4){0.f, 0.f, 0.f, 0.f};
#pragma unroll
        for (int kt = 0; kt < 4; ++kt) {
            u32 w[8];
            {
                int ct = kt * 2;
                float bv = bd2[ct * 16 + lr];
                float v0 = fmaxf(acc2[ct][0] + bv, 0.f), v1 = fmaxf(acc2[ct][1] + bv, 0.f);
                float v2 = fmaxf(acc2[ct][2] + bv, 0.f), v3 = fmaxf(acc2[ct][3] + bv, 0.f);
                u32 hp01 = cvtpk(v0, v1), hp23 = cvtpk(v2, v3);
                u32 lp01 = cvtpk(v0 - bf2f((u16)hp01), v1 - bf2f((u16)(hp01 >> 16)));
                u32 lp23 = cvtpk(v2 - bf2f((u16)hp23), v3 - bf2f((u16)(hp23 >> 16)));
                scr[wrow + lg * 4 + 0][lr] = (hp01 & 0xffffu) | (lp01 << 16);
                scr[wrow + lg * 4 + 1][lr] = (hp01 >> 16) | (lp01 & 0xffff0000u);
                scr[wrow + lg * 4 + 2][lr] = (hp23 & 0xffffu) | (lp23 << 16);
                scr[wrow + lg * 4 + 3][lr] = (hp23 >> 16) | (lp23 & 0xffff0000u);
            }
            if (lg < 2) {
                *(uint4*)&w[0] = *(const uint4*)&scr[wrow + lr][lg * 8];
                *(uint4*)&w[4] = *(const uint4*)&scr[wrow + lr][lg * 8 + 4];
            }
            {
                int ct = kt * 2 + 1;
                float bv = bd2[ct * 16 + lr];
                float v0 = fmaxf(acc2[ct][0] + bv, 0.f), v1 = fmaxf(acc2[ct][1] + bv, 0.f);
                float v2 = fmaxf(acc2[ct][2] + bv, 0.f), v3 = fmaxf(acc2[ct][3] + bv, 0.f);
                u32 hp01 = cvtpk(v0, v1), hp23 = cvtpk(v2, v3);
                u32 lp01 = cvtpk(v0 - bf2f((u16)hp01), v1 - bf2f((u16)(hp01 >> 16)));
                u32 lp23 = cvtpk(v2 - bf2f((u16)hp23), v3 - bf2f((u16)(hp23 >> 16)));
                scr[wrow + lg * 4 + 0][lr] = (hp01 & 0xffffu) | (lp01 << 16);
                scr[wrow + lg * 4 + 1][lr] = (hp01 >> 16) | (lp01 & 0xffff0000u);
                scr[wrow + lg * 4 + 2][lr] = (hp23 & 0xffffu) | (lp23 << 16);
                scr[wrow + lg * 4 + 3][lr] = (hp23 >> 16) | (lp23 & 0xffff0000u);
            }
            if (lg >= 2) {
                *(uint4*)&w[0] = *(const uint4*)&scr[wrow + lr][(lg - 2) * 8];
                *(uint4*)&w[4] = *(const uint4*)&scr[wrow + lr][(lg - 2) * 8 + 4];
            }
            bf8 a3H, a3L;
#pragma unroll
            for (int j = 0; j < 8; ++j) {
                ((u16*)&a3H)[j] = (u16)(w[j] & 0xffffu);
                ((u16*)&a3L)[j] = (u16)(w[j] >> 16);
            }
#pragma unroll
            for (int ct = 0; ct < 8; ++ct) {
                bf8 bH = *(const bf8*)&wbH[40 + kt * 8 + ct][l * 8];
                bf8 bL = *(const bf8*)&wbL[40 + kt * 8 + ct][l * 8];
                acc3[ct] = __builtin_amdgcn_mfma_f32_16x16x32_bf16(a3H, bH, acc3[ct], 0, 0, 0);
                acc3[ct] = __builtin_amdgcn_mfma_f32_16x16x32_bf16(a3L, bH, acc3[ct], 0, 0, 0);
                acc3[ct] = __builtin_amdgcn_mfma_f32_16x16x32_bf16(a3H, bL, acc3[ct], 0, 0, 0);
            }
        }

        // ---- epilogue: softplus -> out[:,42:170) ----
#pragma unroll
        for (int ct = 0; ct < 8; ++ct) {
            float bv = bd3[ct * 16 + lr];
#pragma unroll
            for (int rg = 0; rg < 4; ++rg) {
                int g = row0 + wrow + lg * 4 + rg;
                if (g < n) {
                    float v = acc3[ct][rg] + bv;
                    v = fmaxf(v, 0.f) + __logf(1.f + __expf(-fabsf(v)));
                    out[(size_t)g * 170 + 42 + ct * 16 + lr] = v;
                }
            }
        }
    }
}

// ---------------- launch ----------------

extern "C" void kernel_launch(void* const* d_in, const int* in_sizes, int n_in,
                              void* d_out, int out_size, void* d_ws, size_t ws_size,
                              hipStream_t stream) {
    const float* raw_x = (const float*)d_in[0];
    const int*   ei    = (const int*)d_in[1];
    const float* W1 = (const float*)d_in[2];  const float* b1 = (const float*)d_in[3];
    const float* W2 = (const float*)d_in[4];  const float* b2 = (const float*)d_in[5];
    const float* Wp = (const float*)d_in[6];  const float* bp = (const float*)d_in[7];
    const float* Wd1 = (const float*)d_in[8]; const float* bd1 = (const float*)d_in[9];
    const float* Wd2 = (const float*)d_in[10]; const float* bd2 = (const float*)d_in[11];
    const float* Wd3 = (const float*)d_in[12]; const float* bd3 = (const float*)d_in[13];

    const int n = in_sizes[0] / 128;   // 50000
    const int E = in_sizes[1] / 2;     // 800000
    const int* row = ei;        // source
    const int* col = ei + E;    // target

    float* out = (float*)d_out;

    const int nwg  = (E + CHUNK - 1) / CHUNK;   // 391
    const int nbuk = (n + 63) >> 6;             // 782

    // workspace layout (aligned)
    char* ws = (char*)d_ws;
    auto alloc = [&](size_t bytes) {
        ws = (char*)(((uintptr_t)ws + 255) & ~(uintptr_t)255);
        char* p = ws; ws += bytes; return (void*)p;
    };
    float* dinv   = (float*)alloc((size_t)n * 4);
    int*   rowptr = (int*)alloc((size_t)(n + 4) * 4);
    int*   boff   = (int*)alloc((size_t)(nbuk + 4) * 4);
    int*   bsum   = (int*)alloc((size_t)nbuk * 4);
    int*   M      = (int*)alloc((size_t)nbuk * nwg * 4);
    int*   csrc   = (int*)alloc((size_t)E * 4);
    int2*  ebuf   = (int2*)alloc((size_t)E * 8);
    u16*   hs1b   = (u16*)alloc((size_t)n * 64 * 2);     // bf16 hs1
    u16*   hs2b   = (u16*)alloc((size_t)n * 32 * 2);     // bf16 hs2
    u16*   wswHi  = (u16*)alloc((size_t)89 * 512 * 2);
    u16*   wswLo  = (u16*)alloc((size_t)89 * 512 * 2);

    const int BS = 256;
    auto blocks = [](long long work, int bs) { return (unsigned)((work + bs - 1) / bs); };
    const int ntiles1 = (n + 127) / 128;             // 391 (gemm1 + decoder tiles)

    // ---- graph structure: bucketed counting sort (zero global atomics) ----
    bucket_hist<<<nwg, 256, 0, stream>>>(col, M, E, nbuk, nwg);
    col_scan_wave<<<blocks((long long)nbuk * 64, BS), BS, 0, stream>>>(M, bsum, nbuk, nwg);
    bucket_scan<<<1, 1024, 0, stream>>>(bsum, boff, rowptr, nbuk, n, E);
    bucket_scatter<<<nwg, 256, 0, stream>>>(row, col, M, boff, ebuf, E, nwg);
    bucket_finalize<<<nbuk, 256, 0, stream>>>(ebuf, boff, rowptr, csrc, dinv, n);

    // ---- weight swizzle (independent; includes W1 tiles 73..88) ----
    wswz_kernel<<<89, 64, 0, stream>>>(Wd1, Wd2, Wd3, Wp, W1, wswHi, wswLo);

    // ---- GCN layer 1 via MFMA: raw_x[128] -> 64 (bf16 hs1) ----
    gemm1_mfma<<<391, 512, 0, stream>>>(raw_x, wswHi, wswLo, dinv, hs1b, n, ntiles1);

    // ---- fused agg1 + layer-2 GEMM: hs1 -> hs2 (bf16), x1 never materialized ----
    agg1_gemm2<<<blocks((long long)n * 8, BS), BS, 0, stream>>>(
        rowptr, csrc, hs1b, dinv, b1, W2, hs2b, n);

    // ---- layer-2 aggregation: hs2 -> emb (out[:,0:32)) ----
    agg_finalize_bf16<32, false><<<blocks((long long)n * 4, BS), BS, 0, stream>>>(
        rowptr, csrc, hs2b, dinv, b2, out, n, 170, 0);

    // ---- fully-fused decoder: 8 waves/block, weights resident in LDS ----
    dec_fused<<<256, 512, 0, stream>>>(out, wswHi, wswLo, bp, bd1, bd2, bd3, out, n, ntiles1);
}